// Round 1
// baseline (1130.380 us; speedup 1.0000x reference)
//
#include <hip/hip_runtime.h>
#include <math.h>

#define VOCAB 128000
#define BEAM 5
#define NBLK 32            // partial blocks per beam
#define CH (VOCAB / NBLK)  // 4000 elements per partial block

// ---- workspace layout (float index space on d_ws) ----
#define WS_M  0                 // [5][32] partial max
#define WS_S  160               // [5][32] partial sumexp (rel. to partial max)
#define WS_V  320               // [5][32][5] partial top5 values
#define WS_I  1120              // [5][32][5] partial top5 indices (int)
#define WS_BI 1920              // [5] beam_index (int)
#define WS_TK 1925              // [5] token (int)

// ---- output layout (float index space on d_out) ----
#define KV_PER_ELEMS 10485760            // 5*8*2048*128
#define OUT_SAVE 167772160               // 16 * KV_PER_ELEMS
#define OUT_RP   167774720               // + 5*512
#define OUT_PROB 168414720               // + 5*128000
#define OUT_TOK  168414725
#define OUT_MAXI 168414730

#define PER_BEAM_F4 524288u              // 8*2048*128/4
#define PER_KV_F4   2621440u             // 5 * PER_BEAM_F4
#define TOTAL_F4    41943040u            // 16 * PER_KV_F4

struct KvPtrs { const float4* p[16]; };

// ---------------- kernel 1: per-block online softmax + top-5 ----------------
__global__ __launch_bounds__(256) void beam_topk_partial(
    const float* __restrict__ logits, const float* __restrict__ rp,
    float* __restrict__ ws)
{
    const int beam = blockIdx.y;
    const int blk  = blockIdx.x;
    const int tid  = threadIdx.x;
    const int base = blk * CH;
    const float* __restrict__ x = logits + beam * VOCAB + base;
    const float* __restrict__ r = rp     + beam * VOCAB + base;

    float m = -INFINITY, s = 0.0f;
    float tv0 = -INFINITY, tv1 = -INFINITY, tv2 = -INFINITY, tv3 = -INFINITY, tv4 = -INFINITY;
    int   ti0 = 0x7fffffff, ti1 = 0x7fffffff, ti2 = 0x7fffffff, ti3 = 0x7fffffff, ti4 = 0x7fffffff;

    for (int j = tid; j < CH; j += 256) {
        float v = x[j] * r[j];
        // online softmax accumulation
        if (v > m) { s = s * expf(m - v) + 1.0f; m = v; }
        else       { s += expf(v - m); }
        // top-5 insert, fully static compare-swap chain
        float cv = v; int ci = base + j;
        {
            bool bt; float ov; int oi;
            bt = (cv > tv0) || (cv == tv0 && ci < ti0); ov = tv0; oi = ti0; if (bt) { tv0 = cv; ti0 = ci; cv = ov; ci = oi; }
            bt = (cv > tv1) || (cv == tv1 && ci < ti1); ov = tv1; oi = ti1; if (bt) { tv1 = cv; ti1 = ci; cv = ov; ci = oi; }
            bt = (cv > tv2) || (cv == tv2 && ci < ti2); ov = tv2; oi = ti2; if (bt) { tv2 = cv; ti2 = ci; cv = ov; ci = oi; }
            bt = (cv > tv3) || (cv == tv3 && ci < ti3); ov = tv3; oi = ti3; if (bt) { tv3 = cv; ti3 = ci; cv = ov; ci = oi; }
            bt = (cv > tv4) || (cv == tv4 && ci < ti4); ov = tv4; oi = ti4; if (bt) { tv4 = cv; ti4 = ci; cv = ov; ci = oi; }
        }
    }

    __shared__ float sm[256], ss[256];
    __shared__ float sv[256][5];
    __shared__ int   si[256][5];
    sm[tid] = m; ss[tid] = s;
    sv[tid][0] = tv0; sv[tid][1] = tv1; sv[tid][2] = tv2; sv[tid][3] = tv3; sv[tid][4] = tv4;
    si[tid][0] = ti0; si[tid][1] = ti1; si[tid][2] = ti2; si[tid][3] = ti3; si[tid][4] = ti4;

    for (int off = 128; off > 0; off >>= 1) {
        __syncthreads();
        if (tid < off) {
            int o = tid + off;
            float m2 = sm[o], s2 = ss[o];
            float M = fmaxf(m, m2);
            s = s * expf(m - M) + s2 * expf(m2 - M);
            m = M;
            sm[tid] = m; ss[tid] = s;
            #pragma unroll
            for (int k = 0; k < 5; ++k) {
                float cv = sv[o][k]; int ci = si[o][k];
                bool bt; float ov; int oi;
                bt = (cv > tv0) || (cv == tv0 && ci < ti0); ov = tv0; oi = ti0; if (bt) { tv0 = cv; ti0 = ci; cv = ov; ci = oi; }
                bt = (cv > tv1) || (cv == tv1 && ci < ti1); ov = tv1; oi = ti1; if (bt) { tv1 = cv; ti1 = ci; cv = ov; ci = oi; }
                bt = (cv > tv2) || (cv == tv2 && ci < ti2); ov = tv2; oi = ti2; if (bt) { tv2 = cv; ti2 = ci; cv = ov; ci = oi; }
                bt = (cv > tv3) || (cv == tv3 && ci < ti3); ov = tv3; oi = ti3; if (bt) { tv3 = cv; ti3 = ci; cv = ov; ci = oi; }
                bt = (cv > tv4) || (cv == tv4 && ci < ti4); ov = tv4; oi = ti4; if (bt) { tv4 = cv; ti4 = ci; cv = ov; ci = oi; }
            }
            sv[tid][0] = tv0; sv[tid][1] = tv1; sv[tid][2] = tv2; sv[tid][3] = tv3; sv[tid][4] = tv4;
            si[tid][0] = ti0; si[tid][1] = ti1; si[tid][2] = ti2; si[tid][3] = ti3; si[tid][4] = ti4;
        }
    }
    if (tid == 0) {
        int pb = beam * NBLK + blk;
        ws[WS_M + pb] = m;
        ws[WS_S + pb] = s;
        float* wv = ws + WS_V + pb * 5;
        int*   wi = (int*)ws + WS_I + pb * 5;
        wv[0] = tv0; wv[1] = tv1; wv[2] = tv2; wv[3] = tv3; wv[4] = tv4;
        wi[0] = ti0; wi[1] = ti1; wi[2] = ti2; wi[3] = ti3; wi[4] = ti4;
    }
}

// ---------------- kernel 2: combine partials, 25->5 beam selection ----------------
__global__ __launch_bounds__(64) void beam_select(
    const float* __restrict__ prev, float* __restrict__ ws, float* __restrict__ out)
{
    const int tid = threadIdx.x;
    __shared__ float cur[25];
    __shared__ int   ctok[25];
    int* wsi = (int*)ws;

    if (tid < BEAM) {
        int b = tid;
        float M = -INFINITY;
        for (int p = 0; p < NBLK; ++p) M = fmaxf(M, ws[WS_M + b * NBLK + p]);
        float S = 0.0f;
        for (int p = 0; p < NBLK; ++p) S += ws[WS_S + b * NBLK + p] * expf(ws[WS_M + b * NBLK + p] - M);
        float tv0 = -INFINITY, tv1 = -INFINITY, tv2 = -INFINITY, tv3 = -INFINITY, tv4 = -INFINITY;
        int   ti0 = 0x7fffffff, ti1 = 0x7fffffff, ti2 = 0x7fffffff, ti3 = 0x7fffffff, ti4 = 0x7fffffff;
        for (int p = 0; p < NBLK; ++p) {
            const float* wv = ws + WS_V + (b * NBLK + p) * 5;
            const int*   wi = (int*)ws + WS_I + (b * NBLK + p) * 5;
            #pragma unroll
            for (int k = 0; k < 5; ++k) {
                float cv = wv[k]; int ci = wi[k];
                bool bt; float ov; int oi;
                bt = (cv > tv0) || (cv == tv0 && ci < ti0); ov = tv0; oi = ti0; if (bt) { tv0 = cv; ti0 = ci; cv = ov; ci = oi; }
                bt = (cv > tv1) || (cv == tv1 && ci < ti1); ov = tv1; oi = ti1; if (bt) { tv1 = cv; ti1 = ci; cv = ov; ci = oi; }
                bt = (cv > tv2) || (cv == tv2 && ci < ti2); ov = tv2; oi = ti2; if (bt) { tv2 = cv; ti2 = ci; cv = ov; ci = oi; }
                bt = (cv > tv3) || (cv == tv3 && ci < ti3); ov = tv3; oi = ti3; if (bt) { tv3 = cv; ti3 = ci; cv = ov; ci = oi; }
                bt = (cv > tv4) || (cv == tv4 && ci < ti4); ov = tv4; oi = ti4; if (bt) { tv4 = cv; ti4 = ci; cv = ov; ci = oi; }
            }
        }
        float lse = M + logf(S);
        float pb = prev[b];
        cur[b * 5 + 0] = tv0 - lse + pb; ctok[b * 5 + 0] = ti0;
        cur[b * 5 + 1] = tv1 - lse + pb; ctok[b * 5 + 1] = ti1;
        cur[b * 5 + 2] = tv2 - lse + pb; ctok[b * 5 + 2] = ti2;
        cur[b * 5 + 3] = tv3 - lse + pb; ctok[b * 5 + 3] = ti3;
        cur[b * 5 + 4] = tv4 - lse + pb; ctok[b * 5 + 4] = ti4;
    }
    __syncthreads();
    if (tid == 0) {
        unsigned used = 0;
        int tok0 = 0;
        for (int k = 0; k < 5; ++k) {
            float best = -INFINITY; int bi = 0;
            for (int j = 0; j < 25; ++j) {
                if (!((used >> j) & 1u) && cur[j] > best) { best = cur[j]; bi = j; }
            }
            used |= 1u << bi;
            int srcb = bi / 5;
            int tok  = ctok[bi];
            if (k == 0) tok0 = tok;
            wsi[WS_BI + k] = srcb;
            wsi[WS_TK + k] = tok;
            out[OUT_PROB + k] = best;
            out[OUT_TOK + k]  = (float)tok;
        }
        out[OUT_MAXI] = (float)tok0;
    }
}

// ---------------- kernel 3: KV beam gather (the big one) ----------------
__global__ __launch_bounds__(256) void kv_gather(
    KvPtrs kp, const float* __restrict__ ws, float4* __restrict__ out)
{
    __shared__ int sbi[BEAM];
    __shared__ const float4* sp[16];
    if (threadIdx.x < BEAM) sbi[threadIdx.x] = ((const int*)ws)[WS_BI + threadIdx.x];
    if (threadIdx.x < 16)   sp[threadIdx.x] = kp.p[threadIdx.x];
    __syncthreads();

    const unsigned step = gridDim.x * 256u;
    for (unsigned i = blockIdx.x * 256u + threadIdx.x; i < TOTAL_F4; i += step) {
        unsigned kv  = i / PER_KV_F4;
        unsigned rem = i - kv * PER_KV_F4;
        unsigned b   = rem / PER_BEAM_F4;
        unsigned off = rem - b * PER_BEAM_F4;
        out[i] = sp[kv][(unsigned)sbi[b] * PER_BEAM_F4 + off];
    }
}

// ---------------- kernel 4: repeat_penality gather + token penalty ----------------
__global__ __launch_bounds__(256) void rp_gather(
    const float* __restrict__ rpin, const float* __restrict__ ws,
    const float* __restrict__ pen, float* __restrict__ out)
{
    __shared__ int sbi[BEAM], stk[BEAM];
    if (threadIdx.x < BEAM) {
        sbi[threadIdx.x] = ((const int*)ws)[WS_BI + threadIdx.x];
        stk[threadIdx.x] = ((const int*)ws)[WS_TK + threadIdx.x];
    }
    __syncthreads();
    float p = *pen;
    const unsigned TOT = 160000u;            // f4 count: 5 * 128000/4
    const unsigned step = gridDim.x * 256u;
    const float4* src4 = (const float4*)rpin;
    float4* dst4 = (float4*)(out + OUT_RP);
    for (unsigned i = blockIdx.x * 256u + threadIdx.x; i < TOT; i += step) {
        unsigned b = i / 32000u;
        unsigned off = i - b * 32000u;
        float4 v = src4[(unsigned)sbi[b] * 32000u + off];
        int v0 = (int)off * 4;
        int tk = stk[b];
        unsigned d = (unsigned)(tk - v0);
        if (d < 4u) {
            if (d == 0u) v.x *= p;
            else if (d == 1u) v.y *= p;
            else if (d == 2u) v.z *= p;
            else v.w *= p;
        }
        dst4[i] = v;
    }
}

// ---------------- kernel 5: new_save = concat(save_id[beam_index], token) ----------------
__global__ __launch_bounds__(256) void save_write(
    const int* __restrict__ save_id, const float* __restrict__ ws, float* __restrict__ out)
{
    int e = blockIdx.x * 256 + threadIdx.x;
    if (e >= BEAM * 512) return;
    int b = e >> 9;
    int c = e & 511;
    const int* wsi = (const int*)ws;
    int bi = wsi[WS_BI + b];
    float v = (c < 511) ? (float)save_id[bi * 511 + c] : (float)wsi[WS_TK + b];
    out[OUT_SAVE + e] = v;
}

extern "C" void kernel_launch(void* const* d_in, const int* in_sizes, int n_in,
                              void* d_out, int out_size, void* d_ws, size_t ws_size,
                              hipStream_t stream)
{
    const float* save_rp  = (const float*)d_in[17];
    const int*   save_id  = (const int*)d_in[16];
    const float* prev     = (const float*)d_in[18];
    const float* logits   = (const float*)d_in[20];
    const float* pen      = (const float*)d_in[21];
    float* out = (float*)d_out;
    float* ws  = (float*)d_ws;

    KvPtrs kp;
    for (int i = 0; i < 16; ++i) kp.p[i] = (const float4*)d_in[i];

    dim3 gA(NBLK, BEAM);
    beam_topk_partial<<<gA, 256, 0, stream>>>(logits, save_rp, ws);
    beam_select<<<1, 64, 0, stream>>>(prev, ws, out);
    kv_gather<<<2048, 256, 0, stream>>>(kp, ws, (float4*)out);
    rp_gather<<<625, 256, 0, stream>>>(save_rp, ws, pen, out);
    save_write<<<10, 256, 0, stream>>>(save_id, ws, out);
}